// Round 9
// baseline (999.936 us; speedup 1.0000x reference)
//
#include <hip/hip_runtime.h>
#include <math.h>

#define HWDIM 128
#define IMG   (HWDIM * HWDIM)       // 16384
#define PLANE (4 * 64 * IMG)        // elems of one [B,64,H,W] tensor

typedef __attribute__((ext_vector_type(8))) short bf16x8;
typedef __attribute__((ext_vector_type(4))) float f32x4;
typedef __attribute__((ext_vector_type(4))) int   i32x4;

__device__ __forceinline__ unsigned short f2bf(float f) {
    unsigned u = __builtin_bit_cast(unsigned, f);
    u += 0x7FFFu + ((u >> 16) & 1u);          // RNE
    return (unsigned short)(u >> 16);
}
__device__ __forceinline__ float bf2f(unsigned short h) {
    unsigned u = ((unsigned)h) << 16;
    return __builtin_bit_cast(float, u);
}
__device__ __forceinline__ float sigmoidf_(float x) {
    return 1.f / (1.f + __expf(-x));
}
__device__ __forceinline__ float tanhf_(float x) {
    return 1.f - 2.f / (__expf(2.f * x) + 1.f);
}

// ---- weight prep: W_cell[256][128][3][3] -> Wg2[9][256][128] bf16
//                   W_seq [64][64][3][3]   -> Ws2[9][64][64]   bf16
__global__ void prep_weights_kernel(const float* __restrict__ Wc,
                                    const float* __restrict__ Ws,
                                    unsigned short* __restrict__ Wg2,
                                    unsigned short* __restrict__ Ws2) {
    int i = blockIdx.x * 256 + threadIdx.x;
    if (i < 9 * 256 * 128) {
        int tap = i >> 15, r = i & 32767, co = r >> 7, ci = r & 127;
        Wg2[i] = f2bf(Wc[(co * 128 + ci) * 9 + tap]);
    }
    if (i < 9 * 64 * 64) {
        int tap = i / 4096, r = i & 4095, co = r >> 6, ci = r & 63;
        Ws2[i] = f2bf(Ws[(co * 64 + ci) * 9 + tap]);
    }
}

// ---- seq conv (one timestep): x fp32 CHW -> xout_t fp32 CHW + gx bf16 HWC
// 256 threads / 4 waves; block = 64 px (half row) x 64 couts; K = 576.
// LDS tile padded to 76 shorts/row (16-bank spread for ds_read_b128).
__global__ __launch_bounds__(256, 4) void seq_conv_mfma(
    const float* __restrict__ x,              // [4][64][128][128]
    const unsigned short* __restrict__ Ws2,   // [9][64][64]
    const float* __restrict__ bseq,           // [64]
    float* __restrict__ xout_t,               // [4][64][128][128]
    unsigned short* __restrict__ gx)          // [4][128][128][64] bf16 HWC
{
    __shared__ __align__(16) unsigned char smem[3 * 66 * 76 * 2];  // 30096 B
    unsigned short* tile = (unsigned short*)smem;                  // [3][66][76]
    float*          sbuf = (float*)smem;                           // [64][68]

    const int tid = threadIdx.x;
    const int bid = (blockIdx.x & 7) * 128 + (blockIdx.x >> 3);    // XCD swizzle
    const int b  = bid >> 8;
    const int y  = (bid >> 1) & 127;
    const int x0 = (bid & 1) * 64;

    const float* xb = x + (size_t)b * 64 * IMG;

    // ---- two-phase staging ----
    float4 fa[6], fb[6];
    #pragma unroll
    for (int it = 0; it < 6; ++it) {
        int i = tid + it * 256;
        int xq = i & 15, cip = (i >> 4) & 31, ry = i >> 9;
        int gy = y - 1 + ry;
        int ci = cip * 2;
        float4 va = {0.f, 0.f, 0.f, 0.f}, vb = {0.f, 0.f, 0.f, 0.f};
        if ((unsigned)gy < 128u) {
            va = *(const float4*)(xb + (size_t)ci * IMG + gy * HWDIM + x0 + xq * 4);
            vb = *(const float4*)(xb + (size_t)(ci + 1) * IMG + gy * HWDIM + x0 + xq * 4);
        }
        fa[it] = va; fb[it] = vb;
    }
    float ea = 0.f, eb = 0.f;
    {
        int e = tid & 1, cip = (tid >> 1) & 31, ry = tid >> 6;
        int xt = e ? 65 : 0;
        int gy = y - 1 + ry, gxx = x0 - 1 + xt;
        int ci = cip * 2;
        if (tid < 192 && (unsigned)gy < 128u && (unsigned)gxx < 128u) {
            ea = xb[(size_t)ci * IMG + gy * HWDIM + gxx];
            eb = xb[(size_t)(ci + 1) * IMG + gy * HWDIM + gxx];
        }
    }
    #pragma unroll
    for (int it = 0; it < 6; ++it) {
        int i = tid + it * 256;
        int xq = i & 15, cip = (i >> 4) & 31, ry = i >> 9;
        int ci = cip * 2;
        const float* pa = (const float*)&fa[it];
        const float* pb = (const float*)&fb[it];
        #pragma unroll
        for (int j = 0; j < 4; ++j) {
            unsigned pk = (unsigned)f2bf(pa[j]) | ((unsigned)f2bf(pb[j]) << 16);
            *(unsigned*)(tile + (ry * 66 + 1 + xq * 4 + j) * 76 + ci) = pk;
        }
    }
    if (tid < 192) {
        int e = tid & 1, cip = (tid >> 1) & 31, ry = tid >> 6;
        int xt = e ? 65 : 0;
        unsigned pk = (unsigned)f2bf(ea) | ((unsigned)f2bf(eb) << 16);
        *(unsigned*)(tile + (ry * 66 + xt) * 76 + cip * 2) = pk;
    }
    __syncthreads();

    const int lane = tid & 63;
    const int w = tid >> 6;                 // cout stripe w*16
    const int ln = lane & 15, lg = lane >> 4;

    f32x4 acc[4];
    #pragma unroll
    for (int n = 0; n < 4; ++n) acc[n] = (f32x4){0.f, 0.f, 0.f, 0.f};

    const unsigned short* wbase = Ws2 + (size_t)(w * 16 + ln) * 64 + lg * 8;
    auto WL = [&](int step) -> bf16x8 {
        int tap = step >> 1, kk = step & 1;
        return *(const bf16x8*)(wbase + tap * 4096 + kk * 32);
    };
    auto MS = [&](bf16x8 wf, int step) {
        int tap = step >> 1, kk = step & 1;
        int dy = tap / 3, dxx = tap % 3;
        #pragma unroll
        for (int n = 0; n < 4; ++n) {
            bf16x8 imf = *(const bf16x8*)(tile + (dy * 66 + n * 16 + ln + dxx) * 76 + kk * 32 + lg * 8);
            acc[n] = __builtin_amdgcn_mfma_f32_16x16x32_bf16(wf, imf, acc[n], 0, 0, 0);
        }
    };
    bf16x8 wA = WL(0), wB;
    #pragma unroll
    for (int st = 0; st < 18; st += 2) {
        wB = WL(st + 1);
        MS(wA, st);
        if (st + 2 < 18) wA = WL(st + 2);
        MS(wB, st + 1);
    }

    // epilogue 1: xout fp32 CHW, coalesced (lane -> px)
    const int co = w * 16 + lg * 4;
    #pragma unroll
    for (int r = 0; r < 4; ++r) {
        const float bv = bseq[co + r];
        float* dst = xout_t + ((size_t)b * 64 + co + r) * IMG + (size_t)y * HWDIM + x0;
        #pragma unroll
        for (int n = 0; n < 4; ++n)
            dst[n * 16 + ln] = acc[n][r] + bv;
    }

    __syncthreads();   // tile dead; sbuf takes over

    // epilogue 2: gx bf16 HWC via LDS bounce
    #pragma unroll
    for (int n = 0; n < 4; ++n)
        #pragma unroll
        for (int r = 0; r < 4; ++r)
            sbuf[(n * 16 + ln) * 68 + co + r] = acc[n][r];
    __syncthreads();
    {
        const int px = tid >> 2, cg = tid & 3;
        unsigned pk[8];
        #pragma unroll
        for (int jj = 0; jj < 8; ++jj) {
            int c0 = cg * 16 + jj * 2;
            unsigned short lo = f2bf(sbuf[px * 68 + c0] + bseq[c0]);
            unsigned short hi = f2bf(sbuf[px * 68 + c0 + 1] + bseq[c0 + 1]);
            pk[jj] = (unsigned)lo | ((unsigned)hi << 16);
        }
        unsigned short* dst = gx + ((((size_t)b * 128 + y) * 128) + x0 + px) * 64 + cg * 16;
        i32x4 v0 = { (int)pk[0], (int)pk[1], (int)pk[2], (int)pk[3] };
        i32x4 v1 = { (int)pk[4], (int)pk[5], (int)pk[6], (int)pk[7] };
        *(i32x4*)(dst)     = v0;
        *(i32x4*)(dst + 8) = v1;
    }
}

// ---- gates conv (Cin=128 -> 256 gate-striped) + in-register LSTM epilogue
// 512 threads / 8 waves; block = 2 rows x 64 px. Wave = (stripe s, row rh).
// LDS [4][66][140] bf16 (pad 140 -> 16-bank spread). 2 blocks/CU target.
__global__ __launch_bounds__(512, 4) void gates_lstm_mfma(
    const unsigned short* __restrict__ gxb,   // [4][128][128][64] bf16 (input_t)
    const unsigned short* __restrict__ hin,   // [4][128][128][64] bf16
    const unsigned short* __restrict__ Wg2,   // [9][256][128]
    const float* __restrict__ bcell,          // [256]
    unsigned short* __restrict__ hout,        // [4][128][128][64] bf16
    unsigned short* __restrict__ cbuf,        // [4][128][128][64] bf16 in/out
    float* __restrict__ h32)                  // h_final fp32 CHW (t=7) or null
{
    __shared__ __align__(16) unsigned short tile[4 * 66 * 140];  // 73920 B

    const int tid = threadIdx.x;
    const int bid = (blockIdx.x & 7) * 64 + (blockIdx.x >> 3);   // XCD swizzle (512%8==0)
    const int b  = bid >> 7;            // 0..3
    const int yp = (bid >> 1) & 63;     // row pair
    const int x0 = (bid & 1) * 64;
    const int y0 = yp * 2;

    // ---- staging: 4 rows x 66 xt x 16 chunks (8 from gx, 8 from hin) ----
    #pragma unroll
    for (int it = 0; it < 9; ++it) {
        int i = tid + it * 512;
        if (i < 4224) {
            int ry  = i / 1056;
            int rem = i - ry * 1056;
            int xt  = rem >> 4;
            int g16 = rem & 15;
            int gy = y0 - 1 + ry, gxx = x0 - 1 + xt;
            i32x4 v = {0, 0, 0, 0};
            if ((unsigned)gy < 128u && (unsigned)gxx < 128u) {
                const unsigned short* src = (g16 < 8) ? gxb : hin;
                v = *(const i32x4*)(src + (((size_t)b * 128 + gy) * 128 + gxx) * 64 + (g16 & 7) * 8);
            }
            *(i32x4*)(tile + (ry * 66 + xt) * 140 + ((g16 < 8) ? 0 : 64) + (g16 & 7) * 8) = v;
        }
    }
    __syncthreads();

    const int lane = tid & 63;
    const int wv = tid >> 6;            // 0..7
    const int s = (wv & 3) * 16;        // cout stripe within each gate
    const int rh = wv >> 2;             // output row (0/1)
    const int ln = lane & 15, lg = lane >> 4;
    const int ch = s + ln;

    f32x4 acc[4][4];                    // [m_px][gate]
    #pragma unroll
    for (int m = 0; m < 4; ++m)
        #pragma unroll
        for (int g = 0; g < 4; ++g) acc[m][g] = (f32x4){0.f, 0.f, 0.f, 0.f};

    const unsigned short* wbase = Wg2 + (size_t)ch * 128 + lg * 8;
    auto WLOAD = [&](bf16x8* d, int st) {
        const int tap = st >> 2, kk = st & 3;
        #pragma unroll
        for (int g = 0; g < 4; ++g)
            d[g] = *(const bf16x8*)(wbase + tap * 32768 + g * 8192 + kk * 32);
    };
    auto MSTEP = [&](const bf16x8* wf, int st) {
        const int tap = st >> 2, kk = st & 3;
        const int dy = tap / 3, dxx = tap % 3;
        #pragma unroll
        for (int m = 0; m < 4; ++m) {
            bf16x8 af = *(const bf16x8*)(tile + ((rh + dy) * 66 + m * 16 + ln + dxx) * 140 + kk * 32 + lg * 8);
            #pragma unroll
            for (int g = 0; g < 4; ++g)
                acc[m][g] = __builtin_amdgcn_mfma_f32_16x16x32_bf16(af, wf[g], acc[m][g], 0, 0, 0);
        }
    };

    bf16x8 wA[4], wB[4];
    WLOAD(wA, 0);
    #pragma unroll
    for (int st = 0; st < 36; st += 2) {
        WLOAD(wB, st + 1);
        MSTEP(wA, st);
        if (st + 2 < 36) WLOAD(wA, st + 2);
        MSTEP(wB, st + 1);
    }

    // ---- in-register LSTM pointwise ----
    const int gy = y0 + rh;
    const float bi = bcell[ch], bf_ = bcell[64 + ch];
    const float bg = bcell[128 + ch], bo = bcell[192 + ch];

    #pragma unroll
    for (int m = 0; m < 4; ++m) {
        #pragma unroll
        for (int r = 0; r < 4; ++r) {
            const int px = m * 16 + lg * 4 + r;
            float gi = acc[m][0][r] + bi;
            float gf = acc[m][1][r] + bf_;
            float gg = acc[m][2][r] + bg;
            float go = acc[m][3][r] + bo;
            float si = sigmoidf_(gi);
            float sf = sigmoidf_(gf);
            float tg = tanhf_(gg);
            float so = sigmoidf_(go);
            const size_t pixbase = ((size_t)b * 128 + gy) * 128 + x0 + px;
            const size_t cidx = pixbase * 64 + ch;
            float cold = bf2f(cbuf[cidx]);
            float cn = sf * cold + si * tg;
            cbuf[cidx] = f2bf(cn);
            float hv = so * tanhf_(cn);
            hout[cidx] = f2bf(hv);
            if (h32) h32[((size_t)b * 64 + ch) * IMG + (size_t)gy * HWDIM + x0 + px] = hv;
        }
    }
}

extern "C" void kernel_launch(void* const* d_in, const int* in_sizes, int n_in,
                              void* d_out, int out_size, void* d_ws, size_t ws_size,
                              hipStream_t stream) {
    const float* xinp   = (const float*)d_in[0]; // [8,4,64,128,128]
    const float* W_seq  = (const float*)d_in[1];
    const float* b_seq  = (const float*)d_in[2];
    const float* W_cell = (const float*)d_in[3];
    const float* b_cell = (const float*)d_in[4];

    float* out     = (float*)d_out;
    float* h_final = out;                    // [4,64,128,128] fp32
    float* xout    = out + PLANE;            // [8,4,64,128,128] fp32

    // ws (bf16 elems): c | h0 | h1 | gx | Wg2 | Ws2   (~34.2 MB)
    unsigned short* cbuf = (unsigned short*)d_ws;
    unsigned short* hb0  = cbuf + PLANE;
    unsigned short* hb1  = hb0 + PLANE;
    unsigned short* gxb  = hb1 + PLANE;
    unsigned short* Wg2  = gxb + PLANE;
    unsigned short* Ws2  = Wg2 + 9 * 256 * 128;
    unsigned short* hbufs[2] = { hb0, hb1 };

    hipMemsetAsync(hb0,  0, (size_t)PLANE * sizeof(unsigned short), stream); // h0
    hipMemsetAsync(cbuf, 0, (size_t)PLANE * sizeof(unsigned short), stream); // c0

    prep_weights_kernel<<<1152, 256, 0, stream>>>(W_cell, W_seq, Wg2, Ws2);

    for (int t = 0; t < 8; ++t) {
        seq_conv_mfma<<<1024, 256, 0, stream>>>(
            xinp + (size_t)t * PLANE, Ws2, b_seq, xout + (size_t)t * PLANE, gxb);
        gates_lstm_mfma<<<512, 512, 0, stream>>>(
            gxb, hbufs[t & 1], Wg2, b_cell,
            hbufs[(t + 1) & 1], cbuf,
            (t == 7) ? h_final : (float*)nullptr);
    }
}

// Round 10
// 919.539 us; speedup vs baseline: 1.0874x; 1.0874x over previous
//
#include <hip/hip_runtime.h>
#include <math.h>

#define HWDIM 128
#define IMG   (HWDIM * HWDIM)       // 16384
#define PLANE (4 * 64 * IMG)        // elems of one [B,64,H,W] tensor

typedef __attribute__((ext_vector_type(8))) short bf16x8;
typedef __attribute__((ext_vector_type(4))) float f32x4;
typedef __attribute__((ext_vector_type(4))) int   i32x4;

__device__ __forceinline__ unsigned short f2bf(float f) {
    unsigned u = __builtin_bit_cast(unsigned, f);
    u += 0x7FFFu + ((u >> 16) & 1u);          // RNE
    return (unsigned short)(u >> 16);
}
__device__ __forceinline__ float bf2f(unsigned short h) {
    unsigned u = ((unsigned)h) << 16;
    return __builtin_bit_cast(float, u);
}
__device__ __forceinline__ float sigmoidf_(float x) {
    return 1.f / (1.f + __expf(-x));
}
__device__ __forceinline__ float tanhf_(float x) {
    return 1.f - 2.f / (__expf(2.f * x) + 1.f);
}

// ---- weight prep: W_cell[256][128][3][3] -> Wg2[9][256][128] bf16
//                   W_seq [64][64][3][3]   -> Ws2[9][64][64]   bf16
__global__ void prep_weights_kernel(const float* __restrict__ Wc,
                                    const float* __restrict__ Ws,
                                    unsigned short* __restrict__ Wg2,
                                    unsigned short* __restrict__ Ws2) {
    int i = blockIdx.x * 256 + threadIdx.x;
    if (i < 9 * 256 * 128) {
        int tap = i >> 15, r = i & 32767, co = r >> 7, ci = r & 127;
        Wg2[i] = f2bf(Wc[(co * 128 + ci) * 9 + tap]);
    }
    if (i < 9 * 64 * 64) {
        int tap = i / 4096, r = i & 4095, co = r >> 6, ci = r & 63;
        Ws2[i] = f2bf(Ws[(co * 64 + ci) * 9 + tap]);
    }
}

// ---- seq conv (one timestep): x fp32 CHW -> xout_t fp32 CHW + gx bf16 HWC
__global__ __launch_bounds__(256, 4) void seq_conv_mfma(
    const float* __restrict__ x,              // [4][64][128][128]
    const unsigned short* __restrict__ Ws2,   // [9][64][64]
    const float* __restrict__ bseq,           // [64]
    float* __restrict__ xout_t,               // [4][64][128][128]
    unsigned short* __restrict__ gx)          // [4][128][128][64] bf16 HWC
{
    __shared__ __align__(16) unsigned char smem[3 * 66 * 76 * 2];  // 30096 B
    unsigned short* tile = (unsigned short*)smem;                  // [3][66][76]
    float*          sbuf = (float*)smem;                           // [64][68]

    const int tid = threadIdx.x;
    const int bid = (blockIdx.x & 7) * 128 + (blockIdx.x >> 3);    // XCD swizzle
    const int b  = bid >> 8;
    const int y  = (bid >> 1) & 127;
    const int x0 = (bid & 1) * 64;

    const float* xb = x + (size_t)b * 64 * IMG;

    float4 fa[6], fb[6];
    #pragma unroll
    for (int it = 0; it < 6; ++it) {
        int i = tid + it * 256;
        int xq = i & 15, cip = (i >> 4) & 31, ry = i >> 9;
        int gy = y - 1 + ry;
        int ci = cip * 2;
        float4 va = {0.f, 0.f, 0.f, 0.f}, vb = {0.f, 0.f, 0.f, 0.f};
        if ((unsigned)gy < 128u) {
            va = *(const float4*)(xb + (size_t)ci * IMG + gy * HWDIM + x0 + xq * 4);
            vb = *(const float4*)(xb + (size_t)(ci + 1) * IMG + gy * HWDIM + x0 + xq * 4);
        }
        fa[it] = va; fb[it] = vb;
    }
    float ea = 0.f, eb = 0.f;
    {
        int e = tid & 1, cip = (tid >> 1) & 31, ry = tid >> 6;
        int xt = e ? 65 : 0;
        int gy = y - 1 + ry, gxx = x0 - 1 + xt;
        int ci = cip * 2;
        if (tid < 192 && (unsigned)gy < 128u && (unsigned)gxx < 128u) {
            ea = xb[(size_t)ci * IMG + gy * HWDIM + gxx];
            eb = xb[(size_t)(ci + 1) * IMG + gy * HWDIM + gxx];
        }
    }
    #pragma unroll
    for (int it = 0; it < 6; ++it) {
        int i = tid + it * 256;
        int xq = i & 15, cip = (i >> 4) & 31, ry = i >> 9;
        int ci = cip * 2;
        const float* pa = (const float*)&fa[it];
        const float* pb = (const float*)&fb[it];
        #pragma unroll
        for (int j = 0; j < 4; ++j) {
            unsigned pk = (unsigned)f2bf(pa[j]) | ((unsigned)f2bf(pb[j]) << 16);
            *(unsigned*)(tile + (ry * 66 + 1 + xq * 4 + j) * 76 + ci) = pk;
        }
    }
    if (tid < 192) {
        int e = tid & 1, cip = (tid >> 1) & 31, ry = tid >> 6;
        int xt = e ? 65 : 0;
        unsigned pk = (unsigned)f2bf(ea) | ((unsigned)f2bf(eb) << 16);
        *(unsigned*)(tile + (ry * 66 + xt) * 76 + cip * 2) = pk;
    }
    __syncthreads();

    const int lane = tid & 63;
    const int w = tid >> 6;
    const int ln = lane & 15, lg = lane >> 4;

    f32x4 acc[4];
    #pragma unroll
    for (int n = 0; n < 4; ++n) acc[n] = (f32x4){0.f, 0.f, 0.f, 0.f};

    const unsigned short* wbase = Ws2 + (size_t)(w * 16 + ln) * 64 + lg * 8;
    auto WL = [&](int step) -> bf16x8 {
        int tap = step >> 1, kk = step & 1;
        return *(const bf16x8*)(wbase + tap * 4096 + kk * 32);
    };
    auto MS = [&](bf16x8 wf, int step) {
        int tap = step >> 1, kk = step & 1;
        int dy = tap / 3, dxx = tap % 3;
        #pragma unroll
        for (int n = 0; n < 4; ++n) {
            bf16x8 imf = *(const bf16x8*)(tile + (dy * 66 + n * 16 + ln + dxx) * 76 + kk * 32 + lg * 8);
            acc[n] = __builtin_amdgcn_mfma_f32_16x16x32_bf16(wf, imf, acc[n], 0, 0, 0);
        }
    };
    bf16x8 wA = WL(0), wB;
    #pragma unroll
    for (int st = 0; st < 18; st += 2) {
        wB = WL(st + 1);
        MS(wA, st);
        if (st + 2 < 18) wA = WL(st + 2);
        MS(wB, st + 1);
    }

    const int co = w * 16 + lg * 4;
    #pragma unroll
    for (int r = 0; r < 4; ++r) {
        const float bv = bseq[co + r];
        float* dst = xout_t + ((size_t)b * 64 + co + r) * IMG + (size_t)y * HWDIM + x0;
        #pragma unroll
        for (int n = 0; n < 4; ++n)
            dst[n * 16 + ln] = acc[n][r] + bv;
    }

    __syncthreads();

    #pragma unroll
    for (int n = 0; n < 4; ++n)
        #pragma unroll
        for (int r = 0; r < 4; ++r)
            sbuf[(n * 16 + ln) * 68 + co + r] = acc[n][r];
    __syncthreads();
    {
        const int px = tid >> 2, cg = tid & 3;
        unsigned pk[8];
        #pragma unroll
        for (int jj = 0; jj < 8; ++jj) {
            int c0 = cg * 16 + jj * 2;
            unsigned short lo = f2bf(sbuf[px * 68 + c0] + bseq[c0]);
            unsigned short hi = f2bf(sbuf[px * 68 + c0 + 1] + bseq[c0 + 1]);
            pk[jj] = (unsigned)lo | ((unsigned)hi << 16);
        }
        unsigned short* dst = gx + ((((size_t)b * 128 + y) * 128) + x0 + px) * 64 + cg * 16;
        i32x4 v0 = { (int)pk[0], (int)pk[1], (int)pk[2], (int)pk[3] };
        i32x4 v1 = { (int)pk[4], (int)pk[5], (int)pk[6], (int)pk[7] };
        *(i32x4*)(dst)     = v0;
        *(i32x4*)(dst + 8) = v1;
    }
}

// ---- gates conv + LSTM: weights staged in LDS per tap (double-buffered).
// 512 threads / 8 waves; block = 2 rows x 64 px x 128 couts (chh half).
// Wave = (chs, ph, rh): 16 ch x 4 gates x 32 px x 1 row; acc[2][4].
__global__ __launch_bounds__(512, 1) void gates_lstm_mfma(
    const unsigned short* __restrict__ gxb,   // [4][128][128][64] bf16
    const unsigned short* __restrict__ hin,   // [4][128][128][64] bf16
    const unsigned short* __restrict__ Wg2,   // [9][256][128]
    const float* __restrict__ bcell,          // [256]
    unsigned short* __restrict__ hout,        // [4][128][128][64] bf16
    unsigned short* __restrict__ cbuf,        // [4][128][128][64] bf16 in/out
    float* __restrict__ h32)                  // h_final fp32 CHW (t=7) or null
{
    __shared__ __align__(16) unsigned short tile[4 * 66 * 140];      // 73920 B
    __shared__ __align__(16) unsigned short wlds[2][4][32][136];     // 69632 B

    const int tid = threadIdx.x;
    const int bid = (blockIdx.x & 7) * 128 + (blockIdx.x >> 3);      // XCD swizzle
    const int b   = bid >> 8;            // 0..3
    const int yp  = (bid >> 2) & 63;     // row pair
    const int xh  = (bid >> 1) & 1;
    const int chh = bid & 1;             // cout half (ch base chh*32)
    const int x0  = xh * 64;
    const int y0  = yp * 2;

    // ---- input staging: 4 rows x 66 xt x 16 chunks (8 gx + 8 hin) ----
    #pragma unroll
    for (int it = 0; it < 9; ++it) {
        int i = tid + it * 512;
        if (i < 4224) {
            int ry  = i / 1056;
            int rem = i - ry * 1056;
            int xt  = rem >> 4;
            int g16 = rem & 15;
            int gy = y0 - 1 + ry, gxx = x0 - 1 + xt;
            i32x4 v = {0, 0, 0, 0};
            if ((unsigned)gy < 128u && (unsigned)gxx < 128u) {
                const unsigned short* src = (g16 < 8) ? gxb : hin;
                v = *(const i32x4*)(src + (((size_t)b * 128 + gy) * 128 + gxx) * 64 + (g16 & 7) * 8);
            }
            *(i32x4*)(tile + (ry * 66 + xt) * 140 + ((g16 < 8) ? 0 : 64) + (g16 & 7) * 8) = v;
        }
    }

    // ---- weight staging map: 64 B/thread/tap, fully coalesced ----
    const int wg  = tid >> 7;          // gate 0..3
    const int wch = (tid >> 2) & 31;   // ch within this block's 32
    const int wcq = tid & 3;           // ci quarter
    const unsigned short* wsrc0 = Wg2 + (size_t)(wg * 64 + chh * 32 + wch) * 128 + wcq * 32;

    i32x4 wst[4];
    #pragma unroll
    for (int j = 0; j < 4; ++j)
        wst[j] = *(const i32x4*)(wsrc0 + j * 8);                   // tap 0
    #pragma unroll
    for (int j = 0; j < 4; ++j)
        *(i32x4*)(&wlds[0][wg][wch][wcq * 32 + j * 8]) = wst[j];

    __syncthreads();

    const int lane = tid & 63;
    const int wv = tid >> 6;
    const int chs = wv >> 2;            // 0..1
    const int ph  = (wv >> 1) & 1;      // px half
    const int rh  = wv & 1;             // row
    const int ln = lane & 15, lg = lane >> 4;
    const int ch = chh * 32 + chs * 16 + ln;

    f32x4 acc[2][4];                    // [m_px][gate]
    #pragma unroll
    for (int m = 0; m < 2; ++m)
        #pragma unroll
        for (int g = 0; g < 4; ++g) acc[m][g] = (f32x4){0.f, 0.f, 0.f, 0.f};

    #pragma unroll
    for (int tap = 0; tap < 9; ++tap) {
        // issue next tap's weight loads early (latency hides under MFMAs)
        if (tap < 8) {
            #pragma unroll
            for (int j = 0; j < 4; ++j)
                wst[j] = *(const i32x4*)(wsrc0 + (size_t)(tap + 1) * 32768 + j * 8);
        }
        const int dy = tap / 3, dxx = tap % 3;
        #pragma unroll
        for (int kk = 0; kk < 4; ++kk) {
            bf16x8 wf[4];
            #pragma unroll
            for (int g = 0; g < 4; ++g)
                wf[g] = *(const bf16x8*)(&wlds[tap & 1][g][chs * 16 + ln][kk * 32 + lg * 8]);
            #pragma unroll
            for (int m = 0; m < 2; ++m) {
                bf16x8 af = *(const bf16x8*)(tile + ((rh + dy) * 66 + ph * 32 + m * 16 + ln + dxx) * 140 + kk * 32 + lg * 8);
                #pragma unroll
                for (int g = 0; g < 4; ++g)
                    acc[m][g] = __builtin_amdgcn_mfma_f32_16x16x32_bf16(af, wf[g], acc[m][g], 0, 0, 0);
            }
        }
        // write next tap's weights into the other buffer, then sync
        if (tap < 8) {
            #pragma unroll
            for (int j = 0; j < 4; ++j)
                *(i32x4*)(&wlds[(tap + 1) & 1][wg][wch][wcq * 32 + j * 8]) = wst[j];
        }
        __syncthreads();
    }

    // ---- in-register LSTM pointwise ----
    const int gy = y0 + rh;
    const float bi = bcell[ch], bf_ = bcell[64 + ch];
    const float bg = bcell[128 + ch], bo = bcell[192 + ch];

    #pragma unroll
    for (int m = 0; m < 2; ++m) {
        #pragma unroll
        for (int r = 0; r < 4; ++r) {
            const int px = ph * 32 + m * 16 + lg * 4 + r;
            float gi = acc[m][0][r] + bi;
            float gf = acc[m][1][r] + bf_;
            float gg = acc[m][2][r] + bg;
            float go = acc[m][3][r] + bo;
            float si = sigmoidf_(gi);
            float sf = sigmoidf_(gf);
            float tg = tanhf_(gg);
            float so = sigmoidf_(go);
            const size_t pixbase = ((size_t)b * 128 + gy) * 128 + x0 + px;
            const size_t cidx = pixbase * 64 + ch;
            float cold = bf2f(cbuf[cidx]);
            float cn = sf * cold + si * tg;
            cbuf[cidx] = f2bf(cn);
            float hv = so * tanhf_(cn);
            hout[cidx] = f2bf(hv);
            if (h32) h32[((size_t)b * 64 + ch) * IMG + (size_t)gy * HWDIM + x0 + px] = hv;
        }
    }
}

extern "C" void kernel_launch(void* const* d_in, const int* in_sizes, int n_in,
                              void* d_out, int out_size, void* d_ws, size_t ws_size,
                              hipStream_t stream) {
    const float* xinp   = (const float*)d_in[0]; // [8,4,64,128,128]
    const float* W_seq  = (const float*)d_in[1];
    const float* b_seq  = (const float*)d_in[2];
    const float* W_cell = (const float*)d_in[3];
    const float* b_cell = (const float*)d_in[4];

    float* out     = (float*)d_out;
    float* h_final = out;                    // [4,64,128,128] fp32
    float* xout    = out + PLANE;            // [8,4,64,128,128] fp32

    // ws (bf16 elems): c | h0 | h1 | gx | Wg2 | Ws2   (~34.2 MB)
    unsigned short* cbuf = (unsigned short*)d_ws;
    unsigned short* hb0  = cbuf + PLANE;
    unsigned short* hb1  = hb0 + PLANE;
    unsigned short* gxb  = hb1 + PLANE;
    unsigned short* Wg2  = gxb + PLANE;
    unsigned short* Ws2  = Wg2 + 9 * 256 * 128;
    unsigned short* hbufs[2] = { hb0, hb1 };

    hipMemsetAsync(hb0,  0, (size_t)PLANE * sizeof(unsigned short), stream); // h0
    hipMemsetAsync(cbuf, 0, (size_t)PLANE * sizeof(unsigned short), stream); // c0

    prep_weights_kernel<<<1152, 256, 0, stream>>>(W_cell, W_seq, Wg2, Ws2);

    for (int t = 0; t < 8; ++t) {
        seq_conv_mfma<<<1024, 256, 0, stream>>>(
            xinp + (size_t)t * PLANE, Ws2, b_seq, xout + (size_t)t * PLANE, gxb);
        gates_lstm_mfma<<<1024, 512, 0, stream>>>(
            gxb, hbufs[t & 1], Wg2, b_cell,
            hbufs[(t + 1) & 1], cbuf,
            (t == 7) ? h_final : (float*)nullptr);
    }
}

// Round 11
// 796.061 us; speedup vs baseline: 1.2561x; 1.1551x over previous
//
#include <hip/hip_runtime.h>
#include <math.h>

#define HWDIM 128
#define IMG   (HWDIM * HWDIM)       // 16384
#define PLANE (4 * 64 * IMG)        // elems of one [B,64,H,W] tensor

typedef __attribute__((ext_vector_type(8))) short bf16x8;
typedef __attribute__((ext_vector_type(4))) float f32x4;
typedef __attribute__((ext_vector_type(4))) int   i32x4;

__device__ __forceinline__ unsigned short f2bf(float f) {
    unsigned u = __builtin_bit_cast(unsigned, f);
    u += 0x7FFFu + ((u >> 16) & 1u);          // RNE
    return (unsigned short)(u >> 16);
}
__device__ __forceinline__ float bf2f(unsigned short h) {
    unsigned u = ((unsigned)h) << 16;
    return __builtin_bit_cast(float, u);
}
__device__ __forceinline__ float sigmoidf_(float x) {
    return 1.f / (1.f + __expf(-x));
}
__device__ __forceinline__ float tanhf_(float x) {
    return 1.f - 2.f / (__expf(2.f * x) + 1.f);
}

// ---- weight prep: W_cell[256][128][3][3] -> Wg2[9][256][128] bf16
//                   W_seq [64][64][3][3]   -> Ws2[9][64][64]   bf16
__global__ void prep_weights_kernel(const float* __restrict__ Wc,
                                    const float* __restrict__ Ws,
                                    unsigned short* __restrict__ Wg2,
                                    unsigned short* __restrict__ Ws2) {
    int i = blockIdx.x * 256 + threadIdx.x;
    if (i < 9 * 256 * 128) {
        int tap = i >> 15, r = i & 32767, co = r >> 7, ci = r & 127;
        Wg2[i] = f2bf(Wc[(co * 128 + ci) * 9 + tap]);
    }
    if (i < 9 * 64 * 64) {
        int tap = i / 4096, r = i & 4095, co = r >> 6, ci = r & 63;
        Ws2[i] = f2bf(Ws[(co * 64 + ci) * 9 + tap]);
    }
}

// ---- seq conv (one timestep): x fp32 CHW -> xout_t fp32 CHW + gx bf16 HWC
__global__ __launch_bounds__(256, 4) void seq_conv_mfma(
    const float* __restrict__ x,              // [4][64][128][128]
    const unsigned short* __restrict__ Ws2,   // [9][64][64]
    const float* __restrict__ bseq,           // [64]
    float* __restrict__ xout_t,               // [4][64][128][128]
    unsigned short* __restrict__ gx)          // [4][128][128][64] bf16 HWC
{
    __shared__ __align__(16) unsigned char smem[3 * 66 * 76 * 2];  // 30096 B
    unsigned short* tile = (unsigned short*)smem;                  // [3][66][76]
    float*          sbuf = (float*)smem;                           // [64][68]

    const int tid = threadIdx.x;
    const int bid = (blockIdx.x & 7) * 128 + (blockIdx.x >> 3);    // XCD swizzle
    const int b  = bid >> 8;
    const int y  = (bid >> 1) & 127;
    const int x0 = (bid & 1) * 64;

    const float* xb = x + (size_t)b * 64 * IMG;

    float4 fa[6], fb[6];
    #pragma unroll
    for (int it = 0; it < 6; ++it) {
        int i = tid + it * 256;
        int xq = i & 15, cip = (i >> 4) & 31, ry = i >> 9;
        int gy = y - 1 + ry;
        int ci = cip * 2;
        float4 va = {0.f, 0.f, 0.f, 0.f}, vb = {0.f, 0.f, 0.f, 0.f};
        if ((unsigned)gy < 128u) {
            va = *(const float4*)(xb + (size_t)ci * IMG + gy * HWDIM + x0 + xq * 4);
            vb = *(const float4*)(xb + (size_t)(ci + 1) * IMG + gy * HWDIM + x0 + xq * 4);
        }
        fa[it] = va; fb[it] = vb;
    }
    float ea = 0.f, eb = 0.f;
    {
        int e = tid & 1, cip = (tid >> 1) & 31, ry = tid >> 6;
        int xt = e ? 65 : 0;
        int gy = y - 1 + ry, gxx = x0 - 1 + xt;
        int ci = cip * 2;
        if (tid < 192 && (unsigned)gy < 128u && (unsigned)gxx < 128u) {
            ea = xb[(size_t)ci * IMG + gy * HWDIM + gxx];
            eb = xb[(size_t)(ci + 1) * IMG + gy * HWDIM + gxx];
        }
    }
    #pragma unroll
    for (int it = 0; it < 6; ++it) {
        int i = tid + it * 256;
        int xq = i & 15, cip = (i >> 4) & 31, ry = i >> 9;
        int ci = cip * 2;
        const float* pa = (const float*)&fa[it];
        const float* pb = (const float*)&fb[it];
        #pragma unroll
        for (int j = 0; j < 4; ++j) {
            unsigned pk = (unsigned)f2bf(pa[j]) | ((unsigned)f2bf(pb[j]) << 16);
            *(unsigned*)(tile + (ry * 66 + 1 + xq * 4 + j) * 76 + ci) = pk;
        }
    }
    if (tid < 192) {
        int e = tid & 1, cip = (tid >> 1) & 31, ry = tid >> 6;
        int xt = e ? 65 : 0;
        unsigned pk = (unsigned)f2bf(ea) | ((unsigned)f2bf(eb) << 16);
        *(unsigned*)(tile + (ry * 66 + xt) * 76 + cip * 2) = pk;
    }
    __syncthreads();

    const int lane = tid & 63;
    const int w = tid >> 6;
    const int ln = lane & 15, lg = lane >> 4;

    f32x4 acc[4];
    #pragma unroll
    for (int n = 0; n < 4; ++n) acc[n] = (f32x4){0.f, 0.f, 0.f, 0.f};

    const unsigned short* wbase = Ws2 + (size_t)(w * 16 + ln) * 64 + lg * 8;
    auto WL = [&](int step) -> bf16x8 {
        int tap = step >> 1, kk = step & 1;
        return *(const bf16x8*)(wbase + tap * 4096 + kk * 32);
    };
    auto MS = [&](bf16x8 wf, int step) {
        int tap = step >> 1, kk = step & 1;
        int dy = tap / 3, dxx = tap % 3;
        #pragma unroll
        for (int n = 0; n < 4; ++n) {
            bf16x8 imf = *(const bf16x8*)(tile + (dy * 66 + n * 16 + ln + dxx) * 76 + kk * 32 + lg * 8);
            acc[n] = __builtin_amdgcn_mfma_f32_16x16x32_bf16(wf, imf, acc[n], 0, 0, 0);
        }
    };
    bf16x8 wA = WL(0), wB;
    #pragma unroll
    for (int st = 0; st < 18; st += 2) {
        wB = WL(st + 1);
        MS(wA, st);
        if (st + 2 < 18) wA = WL(st + 2);
        MS(wB, st + 1);
    }

    const int co = w * 16 + lg * 4;
    #pragma unroll
    for (int r = 0; r < 4; ++r) {
        const float bv = bseq[co + r];
        float* dst = xout_t + ((size_t)b * 64 + co + r) * IMG + (size_t)y * HWDIM + x0;
        #pragma unroll
        for (int n = 0; n < 4; ++n)
            dst[n * 16 + ln] = acc[n][r] + bv;
    }

    __syncthreads();

    #pragma unroll
    for (int n = 0; n < 4; ++n)
        #pragma unroll
        for (int r = 0; r < 4; ++r)
            sbuf[(n * 16 + ln) * 68 + co + r] = acc[n][r];
    __syncthreads();
    {
        const int px = tid >> 2, cg = tid & 3;
        unsigned pk[8];
        #pragma unroll
        for (int jj = 0; jj < 8; ++jj) {
            int c0 = cg * 16 + jj * 2;
            unsigned short lo = f2bf(sbuf[px * 68 + c0] + bseq[c0]);
            unsigned short hi = f2bf(sbuf[px * 68 + c0 + 1] + bseq[c0 + 1]);
            pk[jj] = (unsigned)lo | ((unsigned)hi << 16);
        }
        unsigned short* dst = gx + ((((size_t)b * 128 + y) * 128) + x0 + px) * 64 + cg * 16;
        i32x4 v0 = { (int)pk[0], (int)pk[1], (int)pk[2], (int)pk[3] };
        i32x4 v1 = { (int)pk[4], (int)pk[5], (int)pk[6], (int)pk[7] };
        *(i32x4*)(dst)     = v0;
        *(i32x4*)(dst + 8) = v1;
    }
}

// ---- gates conv + LSTM, m97-shaped: block = full row (128 px) x 256 co.
// 512 thr / 8 waves = 4 ch-stripes x 2 px-halves; acc[4 gates][4 px-frags].
// K-loop: 36 stages (kk-major, tap-minor). B = input ci-slice [3][130][36]
// restaged 4x/block; A = 16KB weight slice double-buffered [2][256][40].
__global__ __launch_bounds__(512, 4) void gates_lstm_mfma(
    const unsigned short* __restrict__ gxb,   // [4][128][128][64] bf16
    const unsigned short* __restrict__ hin,   // [4][128][128][64] bf16
    const unsigned short* __restrict__ Wg2,   // [9][256][128]
    const float* __restrict__ bcell,          // [256]
    unsigned short* __restrict__ hout,        // [4][128][128][64] bf16
    unsigned short* __restrict__ cbuf,        // [4][128][128][64] bf16 in/out
    float* __restrict__ h32)                  // h_final fp32 CHW (t=7) or null
{
    __shared__ __align__(16) unsigned short wlds[2][256][40];   // 40960 B
    __shared__ __align__(16) unsigned short btile[3][130][36];  // 28080 B

    const int tid = threadIdx.x;
    const int bid = (blockIdx.x & 7) * 64 + (blockIdx.x >> 3);  // XCD swizzle (512%8==0)
    const int b = bid >> 7;
    const int y = bid & 127;

    const int lane = tid & 63;
    const int wv = tid >> 6;        // 0..7
    const int wm = wv & 3;          // ch stripe
    const int ph = wv >> 2;         // px half
    const int ln = lane & 15, lg = lane >> 4;
    const int ch = wm * 16 + ln;

    // ---- A staging: thread -> 2 chunks of 16B; co = i>>2, g4 = i&3 ----
    const int aco = tid >> 2;              // chunk 0 co (chunk 1: +128)
    const int ag4 = tid & 3;
    const unsigned short* wsrcb = Wg2 + (size_t)aco * 128 + ag4 * 8;

    // ---- B staging map: i = tid + it*512 < 1560; ry=i/520, pxt=(i%520)>>2, g4=i&3
    const size_t pixb = (size_t)b * 128 * 128;

    i32x4 av0, av1, bv[4];
    auto LOADA = [&](int tap, int kk) {
        const unsigned short* p = wsrcb + (size_t)tap * 32768 + kk * 32;
        av0 = *(const i32x4*)(p);
        av1 = *(const i32x4*)(p + 128 * 128);   // co + 128
    };
    auto WRITEA = [&](int buf) {
        *(i32x4*)(&wlds[buf][aco][ag4 * 8])       = av0;
        *(i32x4*)(&wlds[buf][aco + 128][ag4 * 8]) = av1;
    };
    auto LOADB = [&](int kk) {
        const unsigned short* src = ((kk < 2) ? gxb : hin) + pixb * 64 + (kk & 1) * 32;
        #pragma unroll
        for (int it = 0; it < 4; ++it) {
            int i = tid + it * 512;
            i32x4 v = {0, 0, 0, 0};
            if (i < 1560) {
                int ry = i / 520, rem = i - ry * 520;
                int pxt = rem >> 2, g4 = rem & 3;
                int gy = y - 1 + ry, gxx = pxt - 1;
                if ((unsigned)gy < 128u && (unsigned)gxx < 128u)
                    v = *(const i32x4*)(src + ((size_t)gy * 128 + gxx) * 64 + g4 * 8);
            }
            bv[it] = v;
        }
    };
    auto WRITEB = [&]() {
        #pragma unroll
        for (int it = 0; it < 4; ++it) {
            int i = tid + it * 512;
            if (i < 1560) {
                int ry = i / 520, rem = i - ry * 520;
                int pxt = rem >> 2, g4 = rem & 3;
                *(i32x4*)(&btile[ry][pxt][g4 * 8]) = bv[it];
            }
        }
    };

    // ---- prologue: stage A(0,0) and B(0) ----
    LOADA(0, 0);
    LOADB(0);
    WRITEA(0);
    WRITEB();
    __syncthreads();

    f32x4 acc[4][4];                // [gate][px-frag]
    #pragma unroll
    for (int g = 0; g < 4; ++g)
        #pragma unroll
        for (int n = 0; n < 4; ++n) acc[g][n] = (f32x4){0.f, 0.f, 0.f, 0.f};

    for (int kk = 0; kk < 4; ++kk) {
        for (int tap = 0; tap < 9; ++tap) {
            const int s = kk * 9 + tap;
            const int buf = s & 1;
            // issue next stage's loads early (latency hides under MFMAs)
            if (s < 35) {
                const int ntap = (tap == 8) ? 0 : tap + 1;
                const int nkk  = (tap == 8) ? kk + 1 : kk;
                LOADA(ntap, nkk);
            }
            if (tap == 8 && kk < 3) LOADB(kk + 1);

            const int dy = tap / 3, dxx = tap % 3;
            bf16x8 wf[4];
            #pragma unroll
            for (int g = 0; g < 4; ++g)
                wf[g] = *(const bf16x8*)(&wlds[buf][g * 64 + ch][lg * 8]);
            #pragma unroll
            for (int n = 0; n < 4; ++n) {
                bf16x8 af = *(const bf16x8*)(&btile[dy][ph * 64 + n * 16 + ln + dxx][lg * 8]);
                #pragma unroll
                for (int g = 0; g < 4; ++g)
                    acc[g][n] = __builtin_amdgcn_mfma_f32_16x16x32_bf16(af, wf[g], acc[g][n], 0, 0, 0);
            }

            if (s < 35) WRITEA((s + 1) & 1);
            if (tap == 8 && kk < 3) {
                __syncthreads();    // all waves done reading btile
                WRITEB();
            }
            if (s < 35) __syncthreads();
        }
    }

    // ---- in-register LSTM pointwise: lane owns ch, all 4 gates in acc ----
    const float bi = bcell[ch], bf_ = bcell[64 + ch];
    const float bg = bcell[128 + ch], bo = bcell[192 + ch];

    #pragma unroll
    for (int n = 0; n < 4; ++n) {
        #pragma unroll
        for (int r = 0; r < 4; ++r) {
            const int px = ph * 64 + n * 16 + lg * 4 + r;
            float gi = acc[0][n][r] + bi;
            float gf = acc[1][n][r] + bf_;
            float gg = acc[2][n][r] + bg;
            float go = acc[3][n][r] + bo;
            float si = sigmoidf_(gi);
            float sf = sigmoidf_(gf);
            float tg = tanhf_(gg);
            float so = sigmoidf_(go);
            const size_t pixbase = (pixb + (size_t)y * 128 + px);
            const size_t cidx = pixbase * 64 + ch;
            float cold = bf2f(cbuf[cidx]);
            float cn = sf * cold + si * tg;
            cbuf[cidx] = f2bf(cn);
            float hv = so * tanhf_(cn);
            hout[cidx] = f2bf(hv);
            if (h32) h32[((size_t)b * 64 + ch) * IMG + (size_t)y * HWDIM + px] = hv;
        }
    }
}

extern "C" void kernel_launch(void* const* d_in, const int* in_sizes, int n_in,
                              void* d_out, int out_size, void* d_ws, size_t ws_size,
                              hipStream_t stream) {
    const float* xinp   = (const float*)d_in[0]; // [8,4,64,128,128]
    const float* W_seq  = (const float*)d_in[1];
    const float* b_seq  = (const float*)d_in[2];
    const float* W_cell = (const float*)d_in[3];
    const float* b_cell = (const float*)d_in[4];

    float* out     = (float*)d_out;
    float* h_final = out;                    // [4,64,128,128] fp32
    float* xout    = out + PLANE;            // [8,4,64,128,128] fp32

    // ws (bf16 elems): c | h0 | h1 | gx | Wg2 | Ws2   (~34.2 MB)
    unsigned short* cbuf = (unsigned short*)d_ws;
    unsigned short* hb0  = cbuf + PLANE;
    unsigned short* hb1  = hb0 + PLANE;
    unsigned short* gxb  = hb1 + PLANE;
    unsigned short* Wg2  = gxb + PLANE;
    unsigned short* Ws2  = Wg2 + 9 * 256 * 128;
    unsigned short* hbufs[2] = { hb0, hb1 };

    hipMemsetAsync(hb0,  0, (size_t)PLANE * sizeof(unsigned short), stream); // h0
    hipMemsetAsync(cbuf, 0, (size_t)PLANE * sizeof(unsigned short), stream); // c0

    prep_weights_kernel<<<1152, 256, 0, stream>>>(W_cell, W_seq, Wg2, Ws2);

    for (int t = 0; t < 8; ++t) {
        seq_conv_mfma<<<1024, 256, 0, stream>>>(
            xinp + (size_t)t * PLANE, Ws2, b_seq, xout + (size_t)t * PLANE, gxb);
        gates_lstm_mfma<<<512, 512, 0, stream>>>(
            gxb, hbufs[t & 1], Wg2, b_cell,
            hbufs[(t + 1) & 1], cbuf,
            (t == 7) ? h_final : (float*)nullptr);
    }
}